// Round 6
// baseline (96.640 us; speedup 1.0000x reference)
//
#include <hip/hip_runtime.h>

// Per-element MLP 1->32->(32x32)x9->1, leaky relu.
// R6: v_mfma_f32_16x16x32_f16 (K=32 in ONE mfma; the two per-layer MFMAs for
// output rows 0-15/16-31 are fully independent -> no chained-MFMA latency).
// 8 chains x 16 batch per wave = 16 independent chains/SIMD.
// Logical hidden-unit labeling unit=8g+4a+r makes all permutations identity:
// C reg layout == next layer's B slot layout == contiguous bias bytes.
//   lane: g = lane>>4 (k/row group), c = lane&15 (batch col / A row)
//   A_a[row=c][k=8g+j]  = W[8g+j][8*(c>>2)+4a+(c&3)]
//   B[k=8g+j][col=c]    = h[unit 8g+j] of batch c
//   C (a,reg r)         = unit 8g+4a+r of batch c
#define NLAYERS 9
#define HID 32
#define SLOPE 0.01f
#define NCHAIN 8

typedef _Float16 v2h __attribute__((ext_vector_type(2)));
typedef _Float16 v8h __attribute__((ext_vector_type(8)));
typedef float v4f __attribute__((ext_vector_type(4)));

union U8 { v8h v; v2h p[4]; };   // B operand: 8 f16 = 4 VGPRs

__device__ __forceinline__ v2h pk_cvt(float a, float b) {
    return __builtin_bit_cast(v2h, __builtin_amdgcn_cvt_pkrtz(a, b));
}
__device__ __forceinline__ v2h leaky2(v2h t, v2h s) {
    return __builtin_elementwise_max(t, t * s);
}

__global__ __launch_bounds__(256, 2) void mlp_mfma_kernel(
    const float* __restrict__ x,
    const float* __restrict__ W_in,   // [1,32]
    const float* __restrict__ b_in,   // [32]
    const float* __restrict__ W_hid,  // [9,32,32]  W[l][k_in][n_out]
    const float* __restrict__ b_hid,  // [9,32]
    const float* __restrict__ W_out,  // [32,1]
    const float* __restrict__ b_out,  // [1]
    float* __restrict__ out, int N)
{
    // packed f16 bias: [layer][g][j2] = {b[8g+2*j2], b[8g+2*j2+1]}
    __shared__ __align__(16) v2h bias_sh[NLAYERS][4][4];
    for (int t = threadIdx.x; t < NLAYERS * 16; t += blockDim.x) {
        int l = t >> 4, r = t & 15, g = r >> 2, j2 = r & 3;
        bias_sh[l][g][j2] = v2h{(_Float16)b_hid[l * HID + 8 * g + 2 * j2],
                                (_Float16)b_hid[l * HID + 8 * g + 2 * j2 + 1]};
    }
    __syncthreads();

    const int lane = threadIdx.x & 63;
    const int g    = lane >> 4;    // k-group (A/B), row-group (C)
    const int c    = lane & 15;    // batch col; also A output-row

    // ---- resident weight fragments: 9 layers x 2 row-halves x 4 VGPRs ----
    const int outbase = 8 * (c >> 2) + (c & 3);   // +4a for half a
    v8h aW[NLAYERS][2];
#pragma unroll
    for (int l = 0; l < NLAYERS; ++l) {
        const float* Wl = W_hid + l * HID * HID;
#pragma unroll
        for (int a = 0; a < 2; ++a)
#pragma unroll
            for (int j = 0; j < 8; ++j)
                aW[l][a][j] = (_Float16)Wl[(8 * g + j) * HID + outbase + 4 * a];
    }
    // per-lane unit slice 8g..8g+7 of in/out layer params, packed pairs
    v2h win2[4], bin2[4], wout2[4];
#pragma unroll
    for (int u = 0; u < 4; ++u) {
        int d = 8 * g + 2 * u;
        win2[u]  = v2h{(_Float16)W_in[d],  (_Float16)W_in[d + 1]};
        bin2[u]  = v2h{(_Float16)b_in[d],  (_Float16)b_in[d + 1]};
        wout2[u] = v2h{(_Float16)W_out[d], (_Float16)W_out[d + 1]};
    }
    const float bo = b_out[0];
    const v2h slope2 = v2h{(_Float16)SLOPE, (_Float16)SLOPE};
    const v4f z4 = {};

    const int nwaves = (gridDim.x * blockDim.x) >> 6;
    const int wid    = (blockIdx.x * blockDim.x + threadIdx.x) >> 6;
    const int niter  = (N + NCHAIN * 16 - 1) / (NCHAIN * 16);

    // ---- x prefetch for first iteration ----
    float xc[NCHAIN];
#pragma unroll
    for (int ch = 0; ch < NCHAIN; ++ch) {
        int idx = wid * (NCHAIN * 16) + ch * 16 + c;
        xc[ch] = (idx < N) ? x[idx] : 0.0f;
    }

    for (int it = wid; it < niter; it += nwaves) {
        // prefetch next iteration's x
        float xn[NCHAIN];
        {
            int nit = it + nwaves;
#pragma unroll
            for (int ch = 0; ch < NCHAIN; ++ch) {
                int idx = nit * (NCHAIN * 16) + ch * 16 + c;
                xn[ch] = (nit < niter && idx < N) ? x[idx] : 0.0f;
            }
        }

        // ---- input layer ----
        U8 hb[NCHAIN];
#pragma unroll
        for (int ch = 0; ch < NCHAIN; ++ch) {
            _Float16 xh = (_Float16)xc[ch];
            v2h x2 = v2h{xh, xh};
#pragma unroll
            for (int u = 0; u < 4; ++u)
                hb[ch].p[u] = leaky2(x2 * win2[u] + bin2[u], slope2);
        }

        // ---- 9 hidden layers ----
#pragma unroll
        for (int l = 0; l < NLAYERS; ++l) {
            v2h bl0 = bias_sh[l][g][0], bl1 = bias_sh[l][g][1];
            v2h bl2 = bias_sh[l][g][2], bl3 = bias_sh[l][g][3];

            v4f a0[NCHAIN], a1[NCHAIN];
            // all 16 MFMAs are mutually independent
#pragma unroll
            for (int ch = 0; ch < NCHAIN; ++ch) {
                a0[ch] = __builtin_amdgcn_mfma_f32_16x16x32_f16(aW[l][0], hb[ch].v, z4, 0, 0, 0);
                a1[ch] = __builtin_amdgcn_mfma_f32_16x16x32_f16(aW[l][1], hb[ch].v, z4, 0, 0, 0);
            }
#pragma unroll
            for (int ch = 0; ch < NCHAIN; ++ch) {
                hb[ch].p[0] = leaky2(pk_cvt(a0[ch][0], a0[ch][1]) + bl0, slope2);
                hb[ch].p[1] = leaky2(pk_cvt(a0[ch][2], a0[ch][3]) + bl1, slope2);
                hb[ch].p[2] = leaky2(pk_cvt(a1[ch][0], a1[ch][1]) + bl2, slope2);
                hb[ch].p[3] = leaky2(pk_cvt(a1[ch][2], a1[ch][3]) + bl3, slope2);
            }
        }

        // ---- output layer: lane covers units 8g..8g+7; reduce over groups ----
#pragma unroll
        for (int ch = 0; ch < NCHAIN; ++ch) {
            float p = 0.0f;
#pragma unroll
            for (int u = 0; u < 4; ++u) {
                p = fmaf((float)hb[ch].p[u][0], (float)wout2[u][0], p);
                p = fmaf((float)hb[ch].p[u][1], (float)wout2[u][1], p);
            }
            p += __shfl_xor(p, 16, 64);
            p += __shfl_xor(p, 32, 64);
            float o = p + bo;
            int idx = it * (NCHAIN * 16) + ch * 16 + c;
            // spread the 8 chains' stores across the 4 lane-groups
            if (g == (ch & 3) && idx < N) out[idx] = o;
        }

#pragma unroll
        for (int ch = 0; ch < NCHAIN; ++ch) xc[ch] = xn[ch];
    }
}

extern "C" void kernel_launch(void* const* d_in, const int* in_sizes, int n_in,
                              void* d_out, int out_size, void* d_ws, size_t ws_size,
                              hipStream_t stream) {
    const float* x     = (const float*)d_in[0];
    const float* W_in  = (const float*)d_in[1];
    const float* b_in  = (const float*)d_in[2];
    const float* W_hid = (const float*)d_in[3];
    const float* b_hid = (const float*)d_in[4];
    const float* W_out = (const float*)d_in[5];
    const float* b_out = (const float*)d_in[6];
    float* out = (float*)d_out;

    int N = in_sizes[0];
    // 512 blocks x 4 waves = 2048 waves = 2 waves/SIMD; 8192 iterations of
    // 128 batch -> exactly 4 per wave; weights stay VGPR-resident.
    dim3 block(256);
    dim3 grid(512);
    mlp_mfma_kernel<<<grid, block, 0, stream>>>(x, W_in, b_in, W_hid, b_hid,
                                                W_out, b_out, out, N);
}